// Round 2
// baseline (2266.144 us; speedup 1.0000x reference)
//
#include <hip/hip_runtime.h>
#include <hip/hip_bf16.h>

typedef short bf16x8 __attribute__((ext_vector_type(8)));
typedef float f32x4  __attribute__((ext_vector_type(4)));

#define ROWS 104

// ---- LDS byte map (total 157,056 <= 163,840) ----
#define LDS_X    0u          // [104][256] bf16, 512B rows, swizzled
#define LDS_CTX  53248u      // [104][256] bf16
#define LDS_W    106496u     // 49,152B union region:
                             //   weights stage: [96][256] bf16 (QKV) or [256][64] bf16 (out)
#define LDS_Q    (LDS_W)             // [4][32][32] bf16
#define LDS_K    (LDS_W + 8192u)     // [4][32][32] bf16
#define LDS_VT   (LDS_W + 16384u)    // [4][32][32] bf16 (v transposed: [d][s])
#define LDS_ATT  (LDS_W + 24576u)    // [4][32][32] bf16
#define LDS_SC   (LDS_W + 32768u)    // [4][32][32] f32 (rotated cols)
#define LDS_QB   155648u     // [96] f32 qkv bias slice
#define LDS_OB   156032u     // [256] f32 out bias
#define LDS_BYTES 157056u

// room mask per row (bits 0..25)
// room 5 = {0,1,2,3,20}; room 1 = {4,5,6,7,21,22}; room 2 = {8,9,10,11,23,24};
// room 3 = {12..15}; room 4 = {16..19}; row 25 (global) = all.
__constant__ unsigned int MASKROW[26] = {
  0x0210000Fu,0x0210000Fu,0x0210000Fu,0x0210000Fu,
  0x026000F0u,0x026000F0u,0x026000F0u,0x026000F0u,
  0x03800F00u,0x03800F00u,0x03800F00u,0x03800F00u,
  0x0200F000u,0x0200F000u,0x0200F000u,0x0200F000u,
  0x020F0000u,0x020F0000u,0x020F0000u,0x020F0000u,
  0x0210000Fu,
  0x026000F0u,0x026000F0u,
  0x03800F00u,0x03800F00u,
  0x03FFFFFFu
};

__device__ __forceinline__ unsigned int swz(int row, unsigned int b) {
  return b ^ (unsigned int)((row & 7) << 4);
}
__device__ __forceinline__ unsigned short f2bf(float f) {
  unsigned int u = __float_as_uint(f);
  u = (u + 0x7FFFu + ((u >> 16) & 1u)) >> 16;
  return (unsigned short)u;
}

__global__ __launch_bounds__(256, 1)
void brain_fused(const float* __restrict__ x,
                 const float* __restrict__ qkv_w,
                 const float* __restrict__ qkv_b,
                 const float* __restrict__ out_w,
                 const float* __restrict__ out_b,
                 float* __restrict__ out)
{
  __shared__ char smem[LDS_BYTES] __attribute__((aligned(16)));
  const int tid  = threadIdx.x;
  const int lane = tid & 63;
  const int wid  = tid >> 6;
  const int lr   = lane & 15;   // fragment row/col
  const int lg   = lane >> 4;   // fragment k-group
  const size_t row0 = (size_t)blockIdx.x * ROWS;

  // ---- stage x (f32 -> bf16, swizzled) + out_b ----
  {
    const float4* xv = (const float4*)(x + row0 * 256);
    for (int i = 0; i < 26; ++i) {
      int u = tid + i * 256;
      int r = u >> 6, c4 = u & 63;
      float4 v = xv[u];
      uint2 pk;
      pk.x = (unsigned int)f2bf(v.x) | ((unsigned int)f2bf(v.y) << 16);
      pk.y = (unsigned int)f2bf(v.z) | ((unsigned int)f2bf(v.w) << 16);
      *(uint2*)(smem + LDS_X + swz(r, (unsigned)(r * 512 + c4 * 8))) = pk;
    }
    *(float*)(smem + LDS_OB + tid * 4) = out_b[tid];
  }

  const int wm  = wid >> 1;
  const int MT  = wm ? 3 : 4;     // M-tiles this wave (rows 0-63 | 64-111)
  const int mt0 = wm * 4;
  const int nt0 = (wid & 1) * 3;  // N-tiles: cols 0-47 | 48-95 of head slice

  for (int h = 0; h < 8; ++h) {
    __syncthreads();
    // ---- stage qkv_w head slice (96 rows x 256, f32->bf16) + bias ----
    for (int i = 0; i < 24; ++i) {
      int f = tid + i * 256;
      int r = f >> 6, c4 = f & 63;
      int fg = (r >> 5) * 256 + h * 32 + (r & 31);
      float4 v = *(const float4*)(qkv_w + fg * 256 + c4 * 4);
      uint2 pk;
      pk.x = (unsigned int)f2bf(v.x) | ((unsigned int)f2bf(v.y) << 16);
      pk.y = (unsigned int)f2bf(v.z) | ((unsigned int)f2bf(v.w) << 16);
      *(uint2*)(smem + LDS_W + swz(r, (unsigned)(r * 512 + c4 * 8))) = pk;
    }
    if (tid < 96) {
      int fg = (tid >> 5) * 256 + h * 32 + (tid & 31);
      *(float*)(smem + LDS_QB + tid * 4) = qkv_b[fg];
    }
    __syncthreads();

    // ---- QKV GEMM: [104 x 256] @ [256 x 96] ----
    f32x4 acc[4][3];
    const f32x4 zero = {0.f, 0.f, 0.f, 0.f};
#pragma unroll
    for (int i = 0; i < 4; ++i)
#pragma unroll
      for (int j = 0; j < 3; ++j)
        acc[i][j] = zero;

#pragma unroll
    for (int ks = 0; ks < 8; ++ks) {
      unsigned int kb = (unsigned)(ks * 64 + lg * 16);
      bf16x8 a[4], b[3];
#pragma unroll
      for (int i = 0; i < 4; ++i) if (i < MT) {
        int r = (mt0 + i) * 16 + lr;
        a[i] = *(const bf16x8*)(smem + LDS_X + swz(r, (unsigned)(r * 512) + kb));
      }
#pragma unroll
      for (int j = 0; j < 3; ++j) {
        int c = (nt0 + j) * 16 + lr;
        b[j] = *(const bf16x8*)(smem + LDS_W + swz(c, (unsigned)(c * 512) + kb));
      }
#pragma unroll
      for (int i = 0; i < 4; ++i) if (i < MT)
#pragma unroll
        for (int j = 0; j < 3; ++j)
          acc[i][j] = __builtin_amdgcn_mfma_f32_16x16x32_bf16(a[i], b[j], acc[i][j], 0, 0, 0);
    }
    __syncthreads();  // all waves done reading LDS_W before overwrite

    // ---- writeback q/k/v^T (+bias) into W region ----
    {
      float bj[3];
#pragma unroll
      for (int j = 0; j < 3; ++j)
        bj[j] = *(const float*)(smem + LDS_QB + ((nt0 + j) * 16 + lr) * 4);
#pragma unroll
      for (int i = 0; i < 4; ++i) if (i < MT) {
#pragma unroll
        for (int j = 0; j < 3; ++j) {
          int cf = (nt0 + j) * 16 + lr;
          int kind = cf >> 5, d = cf & 31;
#pragma unroll
          for (int r = 0; r < 4; ++r) {
            int rl = (mt0 + i) * 16 + lg * 4 + r;
            if (rl < ROWS) {
              unsigned short hv = f2bf(acc[i][j][r] + bj[j]);
              int bb = rl / 26, s = rl - bb * 26;
              if (kind == 0)
                *(unsigned short*)(smem + LDS_Q + bb * 2048 + swz(s, (unsigned)(s * 64 + d * 2))) = hv;
              else if (kind == 1)
                *(unsigned short*)(smem + LDS_K + bb * 2048 + swz(s, (unsigned)(s * 64 + d * 2))) = hv;
              else
                *(unsigned short*)(smem + LDS_VT + bb * 2048 + swz(d, (unsigned)(d * 64 + s * 2))) = hv;
            }
          }
        }
      }
      // zero V^T pad columns s = 26..31 (must not be NaN: they hit MFMA K-pad)
      for (int i = 0; i < 3; ++i) {
        int idx = tid * 3 + i;  // 0..767 = 4*32*6
        int bb = idx / 192, rem = idx - bb * 192;
        int d = rem / 6, s = 26 + (rem - (rem / 6) * 6);
        *(unsigned short*)(smem + LDS_VT + bb * 2048 + swz(d, (unsigned)(d * 64 + s * 2))) = 0;
      }
    }
    __syncthreads();

    // ---- scores = q @ k^T (wave wid handles batch wid) ----
    {
      const int b = wid;
      unsigned int kq = (unsigned)(lg * 16);
      bf16x8 qa[2], ka[2];
#pragma unroll
      for (int t = 0; t < 2; ++t) {
        int r = t * 16 + lr;
        qa[t] = *(const bf16x8*)(smem + LDS_Q + b * 2048 + swz(r, (unsigned)(r * 64) + kq));
        ka[t] = *(const bf16x8*)(smem + LDS_K + b * 2048 + swz(r, (unsigned)(r * 64) + kq));
      }
      f32x4 sc[2][2];
#pragma unroll
      for (int mt = 0; mt < 2; ++mt)
#pragma unroll
        for (int nt = 0; nt < 2; ++nt) {
          sc[mt][nt] = zero;
          sc[mt][nt] = __builtin_amdgcn_mfma_f32_16x16x32_bf16(qa[mt], ka[nt], sc[mt][nt], 0, 0, 0);
        }
      // store raw scores, column-rotated by row (bank-conflict-free row reads)
#pragma unroll
      for (int mt = 0; mt < 2; ++mt)
#pragma unroll
        for (int nt = 0; nt < 2; ++nt)
#pragma unroll
          for (int r = 0; r < 4; ++r) {
            int s1 = mt * 16 + lg * 4 + r;
            int s2 = nt * 16 + lr;
            *(float*)(smem + LDS_SC + b * 4096 + s1 * 128 + ((s2 + s1) & 31) * 4) = sc[mt][nt][r];
          }
    }
    __syncthreads();

    // ---- masked softmax (lane s1 < 26 owns a row) ----
    {
      const int b = wid;
      if (lane < 26) {
        const int s1 = lane;
        const unsigned int mrow = MASKROW[s1];
        float* scp = (float*)(smem + LDS_SC + b * 4096 + s1 * 128);
        float m = -3.0e38f;
        for (int j = 0; j < 26; ++j)
          if ((mrow >> j) & 1u) m = fmaxf(m, scp[(j + s1) & 31]);
        float sum = 0.f;
        for (int j = 0; j < 26; ++j) {
          float p = 0.f;
          if ((mrow >> j) & 1u) {
            // exp(x/sqrt(32)) = exp2(x * 0.17677670 * 1.4426950)
            p = exp2f((scp[(j + s1) & 31] - m) * 0.25505277f);
            sum += p;
          }
          scp[(j + s1) & 31] = p;
        }
        float rinv = 1.f / sum;
        for (int j = 0; j < 26; ++j) {
          unsigned short hv = f2bf(scp[(j + s1) & 31] * rinv);
          *(unsigned short*)(smem + LDS_ATT + b * 2048 + swz(s1, (unsigned)(s1 * 64 + j * 2))) = hv;
        }
        for (int j = 26; j < 32; ++j)
          *(unsigned short*)(smem + LDS_ATT + b * 2048 + swz(s1, (unsigned)(s1 * 64 + j * 2))) = 0;
      } else if (lane < 32) {
        const int s1 = lane;  // zero pad rows 26..31
        for (int j = 0; j < 32; ++j)
          *(unsigned short*)(smem + LDS_ATT + b * 2048 + swz(s1, (unsigned)(s1 * 64 + j * 2))) = 0;
      }
    }
    __syncthreads();

    // ---- ctx[:, head cols] = attn @ v ----
    {
      const int b = wid;
      unsigned int kq = (unsigned)(lg * 16);
      bf16x8 pa[2], vb[2];
#pragma unroll
      for (int t = 0; t < 2; ++t) {
        int r = t * 16 + lr;
        pa[t] = *(const bf16x8*)(smem + LDS_ATT + b * 2048 + swz(r, (unsigned)(r * 64) + kq));
        vb[t] = *(const bf16x8*)(smem + LDS_VT + b * 2048 + swz(r, (unsigned)(r * 64) + kq));
      }
      f32x4 pv[2][2];
#pragma unroll
      for (int mt = 0; mt < 2; ++mt)
#pragma unroll
        for (int nt = 0; nt < 2; ++nt) {
          pv[mt][nt] = zero;
          pv[mt][nt] = __builtin_amdgcn_mfma_f32_16x16x32_bf16(pa[mt], vb[nt], pv[mt][nt], 0, 0, 0);
        }
#pragma unroll
      for (int mt = 0; mt < 2; ++mt)
#pragma unroll
        for (int nt = 0; nt < 2; ++nt)
#pragma unroll
          for (int r = 0; r < 4; ++r) {
            int s1 = mt * 16 + lg * 4 + r;
            if (s1 < 26) {
              int rl = b * 26 + s1;
              int col = h * 32 + nt * 16 + lr;
              *(unsigned short*)(smem + LDS_CTX + swz(rl, (unsigned)(rl * 512 + col * 2))) =
                  f2bf(pv[mt][nt][r]);
            }
          }
    }
  } // heads

  __syncthreads();

  // ---- output projection: [104 x 256] @ [256 x 256] + out_b ----
  {
    const f32x4 zero = {0.f, 0.f, 0.f, 0.f};
    f32x4 oacc[7][4];
#pragma unroll
    for (int i = 0; i < 7; ++i)
#pragma unroll
      for (int j = 0; j < 4; ++j)
        oacc[i][j] = zero;

    for (int ec = 0; ec < 4; ++ec) {
      // stage out_w[:, ec*64 .. +63] f32->bf16 : [256][64]
      for (int i = 0; i < 16; ++i) {
        int f = tid + i * 256;
        int o = f >> 4, c4 = f & 15;
        float4 v = *(const float4*)(out_w + o * 256 + ec * 64 + c4 * 4);
        uint2 pk;
        pk.x = (unsigned int)f2bf(v.x) | ((unsigned int)f2bf(v.y) << 16);
        pk.y = (unsigned int)f2bf(v.z) | ((unsigned int)f2bf(v.w) << 16);
        *(uint2*)(smem + LDS_W + swz(o, (unsigned)(o * 128 + c4 * 8))) = pk;
      }
      __syncthreads();
#pragma unroll
      for (int ks = 0; ks < 2; ++ks) {
        unsigned int kbc = (unsigned)(ec * 128 + ks * 64 + lg * 16);
        unsigned int kbw = (unsigned)(ks * 64 + lg * 16);
        bf16x8 a[7], b[4];
#pragma unroll
        for (int mt = 0; mt < 7; ++mt) {
          int r = mt * 16 + lr;
          a[mt] = *(const bf16x8*)(smem + LDS_CTX + swz(r, (unsigned)(r * 512) + kbc));
        }
#pragma unroll
        for (int j = 0; j < 4; ++j) {
          int o = (wid * 4 + j) * 16 + lr;
          b[j] = *(const bf16x8*)(smem + LDS_W + swz(o, (unsigned)(o * 128) + kbw));
        }
#pragma unroll
        for (int mt = 0; mt < 7; ++mt)
#pragma unroll
          for (int j = 0; j < 4; ++j)
            oacc[mt][j] = __builtin_amdgcn_mfma_f32_16x16x32_bf16(a[mt], b[j], oacc[mt][j], 0, 0, 0);
      }
      __syncthreads();
    }

#pragma unroll
    for (int mt = 0; mt < 7; ++mt)
#pragma unroll
      for (int j = 0; j < 4; ++j) {
        int o = (wid * 4 + j) * 16 + lr;
        float bo = *(const float*)(smem + LDS_OB + o * 4);
#pragma unroll
        for (int r = 0; r < 4; ++r) {
          int rl = mt * 16 + lg * 4 + r;
          if (rl < ROWS)
            out[(row0 + rl) * 256 + o] = oacc[mt][j][r] + bo;
        }
      }
  }
}

extern "C" void kernel_launch(void* const* d_in, const int* in_sizes, int n_in,
                              void* d_out, int out_size, void* d_ws, size_t ws_size,
                              hipStream_t stream) {
  (void)in_sizes; (void)n_in; (void)d_ws; (void)ws_size; (void)out_size;
  const float* x     = (const float*)d_in[0];
  const float* qkv_w = (const float*)d_in[1];
  const float* qkv_b = (const float*)d_in[2];
  const float* out_w = (const float*)d_in[3];
  const float* out_b = (const float*)d_in[4];
  float* out = (float*)d_out;

  brain_fused<<<dim3(16384 / 4), dim3(256), 0, stream>>>(x, qkv_w, qkv_b, out_w, out_b, out);
}

// Round 3
// 822.788 us; speedup vs baseline: 2.7542x; 2.7542x over previous
//
#include <hip/hip_runtime.h>
#include <hip/hip_bf16.h>

typedef short bf16x8 __attribute__((ext_vector_type(8)));
typedef float f32x4  __attribute__((ext_vector_type(4)));
typedef unsigned short u16;
typedef unsigned int u32;

#define ROWS 104

// ---- LDS byte map (157,056 <= 163,840) ----
#define LDS_X    0u          // [104][256] bf16, 512B rows, swizzled
#define LDS_CTX  53248u      // [104][256] bf16, swizzled
#define LDS_W    106496u     // 49,152B: qkv_w slice [96][256] | out_w chunk [256][64] | attn overlay
#define LDS_Q    (LDS_W)             // [4][32][32] bf16
#define LDS_K    (LDS_W + 8192u)
#define LDS_VT   (LDS_W + 16384u)    // v transposed [d][s]
#define LDS_ATT  (LDS_W + 24576u)
#define LDS_QB   155648u     // [96] f32
#define LDS_OB   156032u     // [256] f32
#define LDS_BYTES 157056u

// ---- workspace layout ----
#define WS_QKVW 0u          // 8 heads x 49152 B pre-swizzled bf16 image
#define WS_OUTW 393216u     // 4 chunks x 32768 B pre-swizzled bf16 image
#define WS_QB   524288u     // 768 f32 (per-head-packed qkv bias)

// mask per row, rows 26..31 dummy (bit0) so pad rows stay finite
__constant__ u32 MASK32[32] = {
  0x0210000Fu,0x0210000Fu,0x0210000Fu,0x0210000Fu,
  0x026000F0u,0x026000F0u,0x026000F0u,0x026000F0u,
  0x03800F00u,0x03800F00u,0x03800F00u,0x03800F00u,
  0x0200F000u,0x0200F000u,0x0200F000u,0x0200F000u,
  0x020F0000u,0x020F0000u,0x020F0000u,0x020F0000u,
  0x0210000Fu,
  0x026000F0u,0x026000F0u,
  0x03800F00u,0x03800F00u,
  0x03FFFFFFu,
  0x1u,0x1u,0x1u,0x1u,0x1u,0x1u
};

__device__ __forceinline__ u32 swz(int row, u32 b) { return b ^ (u32)((row & 7) << 4); }
__device__ __forceinline__ u16 f2bf(float f) {
  u32 u = __float_as_uint(f);
  u = (u + 0x7FFFu + ((u >> 16) & 1u)) >> 16;
  return (u16)u;
}
__device__ __forceinline__ u32 pk2(float a, float b) {
  return (u32)f2bf(a) | ((u32)f2bf(b) << 16);
}

// ---- prep: build pre-swizzled bf16 weight images + packed bias in ws ----
__global__ __launch_bounds__(256)
void prep(const float* __restrict__ qkv_w, const float* __restrict__ qkv_b,
          const float* __restrict__ out_w, unsigned char* __restrict__ ws) {
  int t = blockIdx.x * 256 + threadIdx.x;
  if (t < 24576) {                       // qkv_w: 8 heads x 3072 granules
    int h = t / 3072, rem = t % 3072;
    int r = rem >> 5, c16 = rem & 31;    // r: 0..95 (q0-31,k32-63,v64-95), c16: 16B col
    int fg = (r >> 5) * 256 + h * 32 + (r & 31);
    const float* s = qkv_w + fg * 256 + c16 * 8;
    float4 v0 = *(const float4*)s, v1 = *(const float4*)(s + 4);
    uint4 o;
    o.x = pk2(v0.x, v0.y); o.y = pk2(v0.z, v0.w);
    o.z = pk2(v1.x, v1.y); o.w = pk2(v1.z, v1.w);
    *(uint4*)(ws + WS_QKVW + (u32)h * 49152u + swz(r, (u32)(r * 512 + c16 * 16))) = o;
  } else if (t < 32768) {                // out_w: 4 chunks x 2048 granules
    int g = t - 24576;
    int ec = g >> 11, rem = g & 2047;
    int o_ = rem >> 3, c16 = rem & 7;
    const float* s = out_w + o_ * 256 + ec * 64 + c16 * 8;
    float4 v0 = *(const float4*)s, v1 = *(const float4*)(s + 4);
    uint4 o;
    o.x = pk2(v0.x, v0.y); o.y = pk2(v0.z, v0.w);
    o.z = pk2(v1.x, v1.y); o.w = pk2(v1.z, v1.w);
    *(uint4*)(ws + WS_OUTW + (u32)ec * 32768u + swz(o_, (u32)(o_ * 128 + c16 * 16))) = o;
  } else if (t < 33536) {                // qkv_b packed [8][96]
    int i = t - 32768;
    int h = i / 96, r = i - h * 96;
    int fg = (r >> 5) * 256 + h * 32 + (r & 31);
    ((float*)(ws + WS_QB))[i] = qkv_b[fg];
  }
}

__global__ __launch_bounds__(512, 1)
void brain_fused(const float* __restrict__ x,
                 const unsigned char* __restrict__ ws,
                 const float* __restrict__ out_b,
                 float* __restrict__ out) {
  __shared__ char smem[LDS_BYTES] __attribute__((aligned(16)));
  const int tid  = threadIdx.x;
  const int lane = tid & 63;
  const int wid  = tid >> 6;    // 0..7
  const int lr   = lane & 15;
  const int lg   = lane >> 4;
  const int wn   = wid & 1;     // N-half (QKV) / row-half+d-half (attn)
  const int wm   = wid >> 1;    // M-quarter (QKV) / batch (attn)
  const size_t row0 = (size_t)blockIdx.x * ROWS;
  const f32x4 zero = {0.f, 0.f, 0.f, 0.f};

  // per-lane mask words for softmax rows s1 = wn*16 + lg*4 + r (lane-constant)
  u32 mw[4];
#pragma unroll
  for (int r = 0; r < 4; ++r) mw[r] = MASK32[wn * 16 + lg * 4 + r];

  // ---- stage X (f32 -> bf16, swizzled): 3328 granules ----
#pragma unroll
  for (int i = 0; i < 7; ++i) {
    int g = tid + i * 512;
    if (g < 3328) {
      int r = g >> 5, c16 = g & 31;
      const float* s = x + (row0 + r) * 256 + c16 * 8;
      float4 v0 = *(const float4*)s, v1 = *(const float4*)(s + 4);
      uint4 o;
      o.x = pk2(v0.x, v0.y); o.y = pk2(v0.z, v0.w);
      o.z = pk2(v1.x, v1.y); o.w = pk2(v1.z, v1.w);
      *(uint4*)(smem + LDS_X + swz(r, (u32)(r * 512 + c16 * 16))) = o;
    }
  }
  if (tid < 256) *(float*)(smem + LDS_OB + tid * 4) = out_b[tid];

  const float* qbp = (const float*)(ws + WS_QB);

  for (int h = 0; h < 8; ++h) {
    __syncthreads();  // b0: prev PV done reading ATT/VT; W region free
    // ---- stage W_h: pure 16B memcpy of pre-swizzled image ----
    {
      const unsigned char* src = ws + WS_QKVW + (u32)h * 49152u;
#pragma unroll
      for (int i = 0; i < 6; ++i) {
        int idx = tid + i * 512;
        *(uint4*)(smem + LDS_W + idx * 16) = *(const uint4*)(src + idx * 16);
      }
      if (tid < 96) *(float*)(smem + LDS_QB + tid * 4) = qbp[h * 96 + tid];
    }
    __syncthreads();  // b1

    // ---- QKV GEMM: [104(pad112) x 96] = X @ Wh^T ----
    f32x4 acc[2][3];
#pragma unroll
    for (int i = 0; i < 2; ++i)
#pragma unroll
      for (int j = 0; j < 3; ++j) acc[i][j] = zero;

    const int MT = (wm == 3) ? 1 : 2;   // M tiles {0,1},{2,3},{4,5},{6}
#pragma unroll
    for (int ks = 0; ks < 8; ++ks) {
      u32 kb = (u32)(ks * 64 + lg * 16);
      bf16x8 a[2], b[3];
#pragma unroll
      for (int i = 0; i < 2; ++i) if (i < MT) {
        int r = (wm * 2 + i) * 16 + lr;
        a[i] = *(const bf16x8*)(smem + LDS_X + swz(r, (u32)(r * 512) + kb));
      }
#pragma unroll
      for (int j = 0; j < 3; ++j) {
        int c = (wn * 3 + j) * 16 + lr;
        b[j] = *(const bf16x8*)(smem + LDS_W + swz(c, (u32)(c * 512) + kb));
      }
#pragma unroll
      for (int i = 0; i < 2; ++i) if (i < MT)
#pragma unroll
        for (int j = 0; j < 3; ++j)
          acc[i][j] = __builtin_amdgcn_mfma_f32_16x16x32_bf16(a[i], b[j], acc[i][j], 0, 0, 0);
    }
    __syncthreads();  // b2: all waves done reading W before overlay write

    // ---- writeback q/k/vT (+bias) into overlay ----
    {
      float bj[3];
#pragma unroll
      for (int j = 0; j < 3; ++j)
        bj[j] = *(const float*)(smem + LDS_QB + ((wn * 3 + j) * 16 + lr) * 4);
#pragma unroll
      for (int i = 0; i < 2; ++i) if (i < MT) {
#pragma unroll
        for (int j = 0; j < 3; ++j) {
          int cf = (wn * 3 + j) * 16 + lr;
          int kind = cf >> 5, d = cf & 31;
#pragma unroll
          for (int r = 0; r < 4; ++r) {
            int rl = (wm * 2 + i) * 16 + lg * 4 + r;
            if (rl < ROWS) {
              u16 hv = f2bf(acc[i][j][r] + bj[j]);
              int bb = rl / 26, s = rl - bb * 26;
              if (kind == 0)
                *(u16*)(smem + LDS_Q + bb * 2048 + swz(s, (u32)(s * 64 + d * 2))) = hv;
              else if (kind == 1)
                *(u16*)(smem + LDS_K + bb * 2048 + swz(s, (u32)(s * 64 + d * 2))) = hv;
              else
                *(u16*)(smem + LDS_VT + bb * 2048 + swz(d, (u32)(d * 64 + s * 2))) = hv;
            }
          }
        }
      }
      // zero VT pad cols s=26..31 (P pad cols are 0, but keep V finite)
#pragma unroll
      for (int i = 0; i < 2; ++i) {
        int idx = tid + i * 512;
        if (idx < 768) {
          int bb = idx / 192, rem = idx - bb * 192;
          int d = rem / 6, s = 26 + (rem - (rem / 6) * 6);
          *(u16*)(smem + LDS_VT + bb * 2048 + swz(d, (u32)(d * 64 + s * 2))) = 0;
        }
      }
    }
    __syncthreads();  // b3

    // ---- QK^T (row-half wn of batch wm) + in-register masked softmax ----
    {
      const int b = wm;
      u32 kq = (u32)(lg * 16);
      int sq = wn * 16 + lr;
      bf16x8 qa = *(const bf16x8*)(smem + LDS_Q + b * 2048 + swz(sq, (u32)(sq * 64) + kq));
      bf16x8 ka[2];
#pragma unroll
      for (int t = 0; t < 2; ++t) {
        int sk = t * 16 + lr;
        ka[t] = *(const bf16x8*)(smem + LDS_K + b * 2048 + swz(sk, (u32)(sk * 64) + kq));
      }
      f32x4 sc[2];
#pragma unroll
      for (int nt = 0; nt < 2; ++nt)
        sc[nt] = __builtin_amdgcn_mfma_f32_16x16x32_bf16(qa, ka[nt], zero, 0, 0, 0);

#pragma unroll
      for (int r = 0; r < 4; ++r) {
        u32 m = mw[r];
        float v0 = sc[0][r], v1 = sc[1][r];
        bool m0 = (m >> lr) & 1u, m1 = (m >> (16 + lr)) & 1u;
        float t0 = m0 ? v0 : -3.0e38f;
        float t1 = m1 ? v1 : -3.0e38f;
        float mx = fmaxf(t0, t1);
        mx = fmaxf(mx, __shfl_xor(mx, 1));
        mx = fmaxf(mx, __shfl_xor(mx, 2));
        mx = fmaxf(mx, __shfl_xor(mx, 4));
        mx = fmaxf(mx, __shfl_xor(mx, 8));
        // exp(s/sqrt(32)) = exp2(s * 0.17677670 * 1.4426950)
        float p0 = m0 ? exp2f((v0 - mx) * 0.25505277f) : 0.f;
        float p1 = m1 ? exp2f((v1 - mx) * 0.25505277f) : 0.f;
        float sm = p0 + p1;
        sm += __shfl_xor(sm, 1);
        sm += __shfl_xor(sm, 2);
        sm += __shfl_xor(sm, 4);
        sm += __shfl_xor(sm, 8);
        float ri = __builtin_amdgcn_rcpf(sm);
        int s1 = wn * 16 + lg * 4 + r;
        *(u16*)(smem + LDS_ATT + b * 2048 + swz(s1, (u32)(s1 * 64 + lr * 2))) = f2bf(p0 * ri);
        *(u16*)(smem + LDS_ATT + b * 2048 + swz(s1, (u32)(s1 * 64 + (16 + lr) * 2))) = f2bf(p1 * ri);
      }
    }
    __syncthreads();  // b4

    // ---- PV (d-half wn) + ctx writeback ----
    {
      const int b = wm;
      u32 kq = (u32)(lg * 16);
      bf16x8 pa[2];
#pragma unroll
      for (int t = 0; t < 2; ++t) {
        int rp = t * 16 + lr;
        pa[t] = *(const bf16x8*)(smem + LDS_ATT + b * 2048 + swz(rp, (u32)(rp * 64) + kq));
      }
      int dv = wn * 16 + lr;
      bf16x8 vb = *(const bf16x8*)(smem + LDS_VT + b * 2048 + swz(dv, (u32)(dv * 64) + kq));
      f32x4 pv[2];
#pragma unroll
      for (int t = 0; t < 2; ++t)
        pv[t] = __builtin_amdgcn_mfma_f32_16x16x32_bf16(pa[t], vb, zero, 0, 0, 0);
#pragma unroll
      for (int t = 0; t < 2; ++t)
#pragma unroll
        for (int r = 0; r < 4; ++r) {
          int s1 = t * 16 + lg * 4 + r;
          if (s1 < 26) {
            int rl = b * 26 + s1;
            int col = h * 32 + wn * 16 + lr;
            *(u16*)(smem + LDS_CTX + swz(rl, (u32)(rl * 512 + col * 2))) = f2bf(pv[t][r]);
          }
        }
    }
  } // heads

  // ---- output projection: [104 x 256] @ [256 x 256] + out_b ----
  f32x4 oacc[7][2];
#pragma unroll
  for (int i = 0; i < 7; ++i) { oacc[i][0] = zero; oacc[i][1] = zero; }

  for (int ec = 0; ec < 4; ++ec) {
    __syncthreads();
    const unsigned char* src = ws + WS_OUTW + (u32)ec * 32768u;
#pragma unroll
    for (int i = 0; i < 4; ++i) {
      int idx = tid + i * 512;
      *(uint4*)(smem + LDS_W + idx * 16) = *(const uint4*)(src + idx * 16);
    }
    __syncthreads();
#pragma unroll
    for (int ks = 0; ks < 2; ++ks) {
      u32 kbc = (u32)(ec * 128 + ks * 64 + lg * 16);
      u32 kbw = (u32)(ks * 64 + lg * 16);
      bf16x8 a[7], bw[2];
#pragma unroll
      for (int mt = 0; mt < 7; ++mt) {
        int r = mt * 16 + lr;
        a[mt] = *(const bf16x8*)(smem + LDS_CTX + swz(r, (u32)(r * 512) + kbc));
      }
#pragma unroll
      for (int j = 0; j < 2; ++j) {
        int o = wid * 32 + j * 16 + lr;
        bw[j] = *(const bf16x8*)(smem + LDS_W + swz(o, (u32)(o * 128) + kbw));
      }
#pragma unroll
      for (int mt = 0; mt < 7; ++mt)
#pragma unroll
        for (int j = 0; j < 2; ++j)
          oacc[mt][j] = __builtin_amdgcn_mfma_f32_16x16x32_bf16(a[mt], bw[j], oacc[mt][j], 0, 0, 0);
    }
  }

#pragma unroll
  for (int mt = 0; mt < 7; ++mt)
#pragma unroll
    for (int j = 0; j < 2; ++j) {
      int o = wid * 32 + j * 16 + lr;
      float bo = *(const float*)(smem + LDS_OB + o * 4);
#pragma unroll
      for (int r = 0; r < 4; ++r) {
        int rl = mt * 16 + lg * 4 + r;
        if (rl < ROWS)
          out[(row0 + rl) * 256 + o] = oacc[mt][j][r] + bo;
      }
    }
}

extern "C" void kernel_launch(void* const* d_in, const int* in_sizes, int n_in,
                              void* d_out, int out_size, void* d_ws, size_t ws_size,
                              hipStream_t stream) {
  (void)in_sizes; (void)n_in; (void)out_size; (void)ws_size;
  const float* x     = (const float*)d_in[0];
  const float* qkv_w = (const float*)d_in[1];
  const float* qkv_b = (const float*)d_in[2];
  const float* out_w = (const float*)d_in[3];
  const float* out_b = (const float*)d_in[4];
  unsigned char* ws = (unsigned char*)d_ws;
  float* out = (float*)d_out;

  prep<<<dim3(131), dim3(256), 0, stream>>>(qkv_w, qkv_b, out_w, ws);
  brain_fused<<<dim3(16384 / 4), dim3(512), 0, stream>>>(x, ws, out_b, out);
}

// Round 5
// 628.145 us; speedup vs baseline: 3.6077x; 1.3099x over previous
//
#include <hip/hip_runtime.h>
#include <hip/hip_bf16.h>

typedef short bf16x8 __attribute__((ext_vector_type(8)));
typedef float f32x4  __attribute__((ext_vector_type(4)));
typedef unsigned short u16;
typedef unsigned int u32;

// ---- LDS map: W frag-image 48KB + per-wave 6KB transpose scratch ----
#define LDS_W     0u
#define LDS_SCR   49152u          // + wid*6144 : q/P'/ctx'(2KB) | k(2KB) | v'(2KB)
#define LDS_BYTES 73728u

// ---- workspace ----
#define WS_QKVW 0u          // 8 heads x 48 frags x 1KB  (frag = (ct*8+ks)*1024 + lane*16)
#define WS_OUTW 393216u     // 128 frags x 1KB           (frag = (ft*8+ks)*1024 + lane*16)
#define WS_QB   524288u     // [8][96] f32

// mask rows (bits 0..25); rows 26..31 dummy bit0 keeps pad finite
__constant__ u32 MASK32[32] = {
  0x0210000Fu,0x0210000Fu,0x0210000Fu,0x0210000Fu,
  0x026000F0u,0x026000F0u,0x026000F0u,0x026000F0u,
  0x03800F00u,0x03800F00u,0x03800F00u,0x03800F00u,
  0x0200F000u,0x0200F000u,0x0200F000u,0x0200F000u,
  0x020F0000u,0x020F0000u,0x020F0000u,0x020F0000u,
  0x0210000Fu,
  0x026000F0u,0x026000F0u,
  0x03800F00u,0x03800F00u,
  0x03FFFFFFu,
  0x1u,0x1u,0x1u,0x1u,0x1u,0x1u
};

__device__ __forceinline__ u16 f2bf(float f) {
  u32 u = __float_as_uint(f);
  u = (u + 0x7FFFu + ((u >> 16) & 1u)) >> 16;
  return (u16)u;
}
__device__ __forceinline__ u32 pk2(float a, float b) {
  return (u32)f2bf(a) | ((u32)f2bf(b) << 16);
}
// bijective 64B-row swizzle: XOR on the FULL byte offset (bit6 of row*64
// participates -> invertible GF(2) map; round-3-verified form)
__device__ __forceinline__ u32 sw64(int row, int col2) {
  return (u32)((row * 64 + col2) ^ ((row & 7) << 4));
}

// ---- prep: fragment-order bf16 weight images + packed bias ----
__global__ __launch_bounds__(256)
void prep(const float* __restrict__ qkv_w, const float* __restrict__ qkv_b,
          const float* __restrict__ out_w, unsigned char* __restrict__ ws)
{
  int t = blockIdx.x * 256 + threadIdx.x;
  if (t < 24576) {                       // qkv frags: 8h x 48fr x 64 lanes
    int h = t / 3072, rem = t - h * 3072;
    int fr = rem >> 6, ln = rem & 63;
    int ct = fr >> 3, ks = fr & 7;
    int lr = ln & 15, lg = ln >> 4;
    int fg = (ct >> 1) * 256 + h * 32 + (ct & 1) * 16 + lr;
    const float* s = qkv_w + fg * 256 + ks * 32 + lg * 8;
    float4 v0 = *(const float4*)s, v1 = *(const float4*)(s + 4);
    uint4 o;
    o.x = pk2(v0.x, v0.y); o.y = pk2(v0.z, v0.w);
    o.z = pk2(v1.x, v1.y); o.w = pk2(v1.z, v1.w);
    *(uint4*)(ws + WS_QKVW + (u32)h * 49152u + (u32)fr * 1024u + (u32)ln * 16u) = o;
  } else if (t < 32768) {                // outw frags: 128fr x 64 lanes
    int g = t - 24576;
    int fr = g >> 6, ln = g & 63;
    int ft = fr >> 3, ks = fr & 7;
    int lr = ln & 15, lg = ln >> 4;
    const float* s = out_w + (ft * 16 + lr) * 256 + ks * 32 + lg * 8;
    float4 v0 = *(const float4*)s, v1 = *(const float4*)(s + 4);
    uint4 o;
    o.x = pk2(v0.x, v0.y); o.y = pk2(v0.z, v0.w);
    o.z = pk2(v1.x, v1.y); o.w = pk2(v1.z, v1.w);
    *(uint4*)(ws + WS_OUTW + (u32)fr * 1024u + (u32)ln * 16u) = o;
  } else if (t < 33536) {                // qkv bias [8][96]
    int i = t - 32768;
    int h = i / 96, j = i - h * 96;
    int ct = j >> 4, lr = j & 15;
    ((float*)(ws + WS_QB))[i] = qkv_b[(ct >> 1) * 256 + h * 32 + (ct & 1) * 16 + lr];
  }
}

__global__ __launch_bounds__(256, 2)
void brain_fused(const float* __restrict__ x,
                 const unsigned char* __restrict__ ws,
                 const float* __restrict__ out_b,
                 float* __restrict__ out)
{
  __shared__ char smem[LDS_BYTES] __attribute__((aligned(16)));
  const int tid  = threadIdx.x;
  const int lane = tid & 63;
  const int wid  = tid >> 6;          // 0..3 = batch within block
  const int lr   = lane & 15;
  const int lg   = lane >> 4;
  const size_t rb = (size_t)blockIdx.x * 104 + (size_t)wid * 26;
  const f32x4 zero = {0.f, 0.f, 0.f, 0.f};
  const u32 sb = LDS_SCR + (u32)wid * 6144u;  // q/P'/ctx' @ sb, k @ +2048, v' @ +4096

  // ---- x A-fragments into registers (reused for all 8 heads) ----
  bf16x8 af[2][8];
#pragma unroll
  for (int st = 0; st < 2; ++st) {
    int s = st * 16 + lr;
    const float* xp = x + (rb + (size_t)(s < 26 ? s : 0)) * 256;
#pragma unroll
    for (int ks = 0; ks < 8; ++ks) {
      const float* p = xp + ks * 32 + lg * 8;
      float4 v0 = *(const float4*)p, v1 = *(const float4*)(p + 4);
      union { u32 u[4]; bf16x8 v; } tt;
      tt.u[0] = pk2(v0.x, v0.y); tt.u[1] = pk2(v0.z, v0.w);
      tt.u[2] = pk2(v1.x, v1.y); tt.u[3] = pk2(v1.z, v1.w);
      af[st][ks] = tt.v;
    }
  }

  // zero v' pad cols s=26..31 once (avoid NaN*0 in PV k-dim)
#pragma unroll
  for (int i = 0; i < 3; ++i) {
    int idx = lane * 3 + i;            // 0..191
    int d = idx / 6, s = 26 + idx % 6;
    *(u16*)(smem + sb + 4096u + sw64(d, s * 2)) = 0;
  }

  const u32 mq0 = MASK32[lr];
  const u32 mq1 = MASK32[16 + lr];
  const float* qb = (const float*)(ws + WS_QB);

  // stage W(0)
#pragma unroll
  for (int i = 0; i < 12; ++i) {
    int idx = tid + i * 256;
    *(uint4*)(smem + LDS_W + (u32)idx * 16u) = *(const uint4*)(ws + WS_QKVW + (u32)idx * 16u);
  }
  __syncthreads();

  bf16x8 cf[8][2];                     // ctx frags (A-operand of out-proj)

#pragma unroll
  for (int h = 0; h < 8; ++h) {
    // ---- QKV GEMM: batch rows x 96 feats, K=256 ----
    f32x4 acc[2][6];
#pragma unroll
    for (int st = 0; st < 2; ++st)
#pragma unroll
      for (int ct = 0; ct < 6; ++ct) acc[st][ct] = zero;
#pragma unroll
    for (int ks = 0; ks < 8; ++ks) {
      bf16x8 bw[6];
#pragma unroll
      for (int ct = 0; ct < 6; ++ct)
        bw[ct] = *(const bf16x8*)(smem + LDS_W + (u32)((ct * 8 + ks) * 1024) + (u32)lane * 16u);
#pragma unroll
      for (int st = 0; st < 2; ++st)
#pragma unroll
        for (int ct = 0; ct < 6; ++ct)
          acc[st][ct] = __builtin_amdgcn_mfma_f32_16x16x32_bf16(af[st][ks], bw[ct], acc[st][ct], 0, 0, 0);
    }
    __syncthreads();  // b1: all waves done reading W(h)

    // stage W(h+1) — overlaps the attention below
    if (h < 7) {
#pragma unroll
      for (int i = 0; i < 12; ++i) {
        int idx = tid + i * 256;
        *(uint4*)(smem + LDS_W + (u32)idx * 16u) =
            *(const uint4*)(ws + WS_QKVW + (u32)(h + 1) * 49152u + (u32)idx * 16u);
      }
    }

    // bias
    float bb[6];
#pragma unroll
    for (int ct = 0; ct < 6; ++ct) bb[ct] = qb[h * 96 + ct * 16 + lr];

    // ---- scratch writes: q[s][d], k[s][d], v'[d][s] (bf16, 64B swizzled rows) ----
#pragma unroll
    for (int st = 0; st < 2; ++st)
#pragma unroll
      for (int ct = 0; ct < 6; ++ct)
#pragma unroll
        for (int r = 0; r < 4; ++r) {
          int s = st * 16 + lg * 4 + r;
          if (s < 26) {
            u16 hv = f2bf(acc[st][ct][r] + bb[ct]);
            int d = (ct & 1) * 16 + lr;
            u32 a;
            if (ct < 2)      a = sb +         sw64(s, d * 2);
            else if (ct < 4) a = sb + 2048u + sw64(s, d * 2);
            else             a = sb + 4096u + sw64(d, s * 2);
            *(u16*)(smem + a) = hv;
          }
        }

    // ---- frag reads (row-slice layout) ----
    bf16x8 qf[2], kf[2], vf[2];
#pragma unroll
    for (int t = 0; t < 2; ++t) {
      u32 ro = sw64(t * 16 + lr, lg * 16);
      qf[t] = *(const bf16x8*)(smem + sb + ro);
      kf[t] = *(const bf16x8*)(smem + sb + 2048u + ro);
      vf[t] = *(const bf16x8*)(smem + sb + 4096u + ro);
    }

    // ---- scores^T = K * Q^T ----
    f32x4 sc[2][2];  // [s_k half][q half]
#pragma unroll
    for (int st = 0; st < 2; ++st)
#pragma unroll
      for (int qt = 0; qt < 2; ++qt)
        sc[st][qt] = __builtin_amdgcn_mfma_f32_16x16x32_bf16(kf[st], qf[qt], zero, 0, 0, 0);

    // ---- masked softmax over s_k (per q column), write P'[q][s] over q-region ----
#pragma unroll
    for (int qt = 0; qt < 2; ++qt) {
      u32 mrow = qt ? mq1 : mq0;
      float mx = -3.0e38f;
#pragma unroll
      for (int st = 0; st < 2; ++st)
#pragma unroll
        for (int r = 0; r < 4; ++r) {
          int sk = st * 16 + lg * 4 + r;
          if ((mrow >> sk) & 1u) mx = fmaxf(mx, sc[st][qt][r]);
        }
      mx = fmaxf(mx, __shfl_xor(mx, 16));
      mx = fmaxf(mx, __shfl_xor(mx, 32));
      float pex[2][4];
      float sum = 0.f;
#pragma unroll
      for (int st = 0; st < 2; ++st)
#pragma unroll
        for (int r = 0; r < 4; ++r) {
          int sk = st * 16 + lg * 4 + r;
          // exp(s/sqrt(32)) = exp2(s * log2(e)/sqrt(32))
          float p = ((mrow >> sk) & 1u) ? exp2f((sc[st][qt][r] - mx) * 0.25505276f) : 0.f;
          pex[st][r] = p; sum += p;
        }
      sum += __shfl_xor(sum, 16);
      sum += __shfl_xor(sum, 32);
      float ri = __builtin_amdgcn_rcpf(sum);
      int q = qt * 16 + lr;
#pragma unroll
      for (int st = 0; st < 2; ++st)
#pragma unroll
        for (int r = 0; r < 4; ++r) {
          int sk = st * 16 + lg * 4 + r;
          *(u16*)(smem + sb + sw64(q, sk * 2)) = f2bf(pex[st][r] * ri);
        }
    }

    // ---- ctx^T = V^T * P^T ----
    bf16x8 pf[2];
#pragma unroll
    for (int qt = 0; qt < 2; ++qt)
      pf[qt] = *(const bf16x8*)(smem + sb + sw64(qt * 16 + lr, lg * 16));
    f32x4 pv[2][2];  // [d half][q half]
#pragma unroll
    for (int dt = 0; dt < 2; ++dt)
#pragma unroll
      for (int qt = 0; qt < 2; ++qt)
        pv[dt][qt] = __builtin_amdgcn_mfma_f32_16x16x32_bf16(vf[dt], pf[qt], zero, 0, 0, 0);

    // ctx'[q][d] over q-region, then read ctx frags
#pragma unroll
    for (int dt = 0; dt < 2; ++dt)
#pragma unroll
      for (int qt = 0; qt < 2; ++qt)
#pragma unroll
        for (int r = 0; r < 4; ++r) {
          int d = dt * 16 + lg * 4 + r;
          int q = qt * 16 + lr;
          *(u16*)(smem + sb + sw64(q, d * 2)) = f2bf(pv[dt][qt][r]);
        }
#pragma unroll
    for (int qt = 0; qt < 2; ++qt)
      cf[h][qt] = *(const bf16x8*)(smem + sb + sw64(qt * 16 + lr, lg * 16));
    __syncthreads();  // b2: W(h+1) staged
  }

  // ---- out-projection: out[q][f] = sum_h ctx_h @ outw_h^T + out_b ----
#pragma unroll
  for (int fc = 0; fc < 4; ++fc) {
    f32x4 oa[2][4];
#pragma unroll
    for (int j = 0; j < 4; ++j) {
      float bo = out_b[(fc * 4 + j) * 16 + lr];
      f32x4 bv = {bo, bo, bo, bo};
      oa[0][j] = bv; oa[1][j] = bv;
    }
#pragma unroll
    for (int ks = 0; ks < 8; ++ks) {
      bf16x8 bw[4];
#pragma unroll
      for (int j = 0; j < 4; ++j)
        bw[j] = *(const bf16x8*)(ws + WS_OUTW + (u32)(((fc * 4 + j) * 8 + ks) * 1024) + (u32)lane * 16u);
#pragma unroll
      for (int qt = 0; qt < 2; ++qt)
#pragma unroll
        for (int j = 0; j < 4; ++j)
          oa[qt][j] = __builtin_amdgcn_mfma_f32_16x16x32_bf16(cf[ks][qt], bw[j], oa[qt][j], 0, 0, 0);
    }
#pragma unroll
    for (int qt = 0; qt < 2; ++qt)
#pragma unroll
      for (int j = 0; j < 4; ++j)
#pragma unroll
        for (int r = 0; r < 4; ++r) {
          int qrow = qt * 16 + lg * 4 + r;
          if (qrow < 26)
            out[(rb + (size_t)qrow) * 256 + (fc * 4 + j) * 16 + lr] = oa[qt][j][r];
        }
  }
}

extern "C" void kernel_launch(void* const* d_in, const int* in_sizes, int n_in,
                              void* d_out, int out_size, void* d_ws, size_t ws_size,
                              hipStream_t stream) {
  (void)in_sizes; (void)n_in; (void)out_size; (void)ws_size;
  const float* x     = (const float*)d_in[0];
  const float* qkv_w = (const float*)d_in[1];
  const float* qkv_b = (const float*)d_in[2];
  const float* out_w = (const float*)d_in[3];
  const float* out_b = (const float*)d_in[4];
  unsigned char* ws = (unsigned char*)d_ws;
  float* out = (float*)d_out;

  prep<<<dim3(131), dim3(256), 0, stream>>>(qkv_w, qkv_b, out_w, ws);
  brain_fused<<<dim3(4096), dim3(256), 0, stream>>>(x, ws, out_b, out);
}